// Round 4
// baseline (1162.238 us; speedup 1.0000x reference)
//
#include <hip/hip_runtime.h>

#define N_NODES 100000
#define N_EDGES 800000
#define N_ETYPES 5
#define NUM_GRAPHS 64
#define IN_DIM 23
#define HID_DIM 128
#define OUT_DIM 64
#define CAP 24                 // srcs per bucket row (pure srcs; cnt is dense array)
#define OVF_ENTRIES 4096

typedef unsigned short u16;
using short8 = __attribute__((ext_vector_type(8))) short;
using f32x4  = __attribute__((ext_vector_type(4))) float;

__device__ __forceinline__ float bf2f(u16 v) {
    union { unsigned u; float f; } x; x.u = ((unsigned)v) << 16; return x.f;
}
__device__ __forceinline__ u16 f2bf(float f) {
    union { float f; unsigned u; } x; x.f = f;
    unsigned r = x.u + 0x7fff + ((x.u >> 16) & 1);   // RNE
    return (u16)(r >> 16);
}

// ---------------- prep: W1t/W2t/b1s (bf16, transposed, zero-padded) ----------------
__global__ __launch_bounds__(256) void k_prep(const float* __restrict__ W1,
                                              const float* __restrict__ W2,
                                              const float* __restrict__ b1,
                                              u16* __restrict__ w1t,
                                              u16* __restrict__ w2t,
                                              float* __restrict__ b1s) {
    int stride = gridDim.x * 256;
    int g0 = blockIdx.x * 256 + threadIdx.x;
    // w1t[hid][k], k = t*32 + f : 128 x 160
    for (int i = g0; i < HID_DIM * 160; i += stride) {
        int hid = i / 160, k = i - hid * 160;
        int t = k >> 5, f = k & 31;
        w1t[i] = (f < IN_DIM) ? f2bf(W1[((size_t)t * IN_DIM + f) * HID_DIM + hid]) : (u16)0;
    }
    // w2t[t][out][k] : 5 x 64 x 128
    for (int i = g0; i < N_ETYPES * OUT_DIM * HID_DIM; i += stride) {
        int t = i >> 13, r = i & 8191;
        int out = r >> 7, k = r & 127;
        w2t[i] = f2bf(W2[((size_t)t * HID_DIM + k) * OUT_DIM + out]);
    }
    for (int i = g0; i < HID_DIM; i += stride) {
        float s = 0.f;
        #pragma unroll
        for (int t = 0; t < N_ETYPES; ++t) s += b1[t * HID_DIM + i];
        b1s[i] = s;
    }
}

// ---------------- xb: x -> bf16, padded to 24 cols ----------------
__global__ __launch_bounds__(256) void k_xb(const float* __restrict__ x,
                                            u16* __restrict__ xb) {
    int i = blockIdx.x * 256 + threadIdx.x;
    if (i >= N_NODES * 24) return;
    int n = i / 24, f = i - n * 24;
    xb[i] = (f < IN_DIM) ? f2bf(x[(size_t)n * IN_DIM + f]) : (u16)0;
}

// ---------------- adjacency fill ----------------
__global__ __launch_bounds__(256) void k_fill(const int* __restrict__ edges,
                                              int* __restrict__ cnt,
                                              int* __restrict__ bucket,
                                              int* __restrict__ ovfn,
                                              long long* __restrict__ ovf) {
    int e = blockIdx.x * 256 + threadIdx.x;
    int t = blockIdx.y;
    if (e >= N_EDGES) return;
    int src = edges[((size_t)t * 2 + 0) * N_EDGES + e];
    int dst = edges[((size_t)t * 2 + 1) * N_EDGES + e];
    int row = t * N_NODES + dst;
    int pos = atomicAdd(&cnt[row], 1);
    if (pos < CAP) {
        bucket[(size_t)row * CAP + pos] = src;
    } else {
        int oi = atomicAdd(ovfn, 1);
        if (oi < OVF_ENTRIES) ovf[oi] = ((long long)row << 32) | (unsigned)src;
    }
}

// ---------------- fused: gather(all etypes) -> MFMA L1+relu -> MFMA L2 -> g ----------------
__global__ __launch_bounds__(256) void k_fused(const int* __restrict__ cnt,
                                               const int* __restrict__ bucket,
                                               const int* __restrict__ ovfn_g,
                                               const long long* __restrict__ ovf,
                                               const u16* __restrict__ xb,
                                               const u16* __restrict__ w1t,
                                               const u16* __restrict__ w2t,
                                               const float* __restrict__ b1s,
                                               u16* __restrict__ g,
                                               int gt0, int gt1) {
    __shared__ u16 s_a[64 * 168];     // [64][160+8pad]  21504 B
    __shared__ u16 s_h1[64 * 136];    // [64][128+8pad]  17408 B
    __shared__ u16 s_out[64 * 72];    // [64][64+8pad]    9216 B
    int tid = threadIdx.x;
    int base = blockIdx.x * 64;

    // ---- phase G: gather, half-wave per (node, etype) ----
    {
        int hw = tid >> 5;            // 0..7
        int f = tid & 31;
        int lanebase = tid & 32;
        for (int p = hw; p < 64 * N_ETYPES; p += 8) {
            int node = p & 63, t = p >> 6;
            int n = base + node;
            float acc = 0.f;
            if (n < N_NODES) {
                int row = t * N_NODES + n;
                int c = cnt[row];
                int bval = 0;
                if (f < CAP) bval = bucket[(size_t)row * CAP + f];
                int kmax = c < CAP ? c : CAP;
                acc = (f < CAP) ? bf2f(xb[(size_t)n * 24 + f]) : 0.f;  // self (col 23 = 0)
                for (int k = 0; k < kmax; ++k) {
                    int src = __shfl(bval, lanebase + k);
                    if (f < CAP) acc += bf2f(xb[(size_t)src * 24 + f]);
                }
                if (c > CAP) {                     // rare exact path
                    int nov = *ovfn_g; if (nov > OVF_ENTRIES) nov = OVF_ENTRIES;
                    for (int i = 0; i < nov; ++i) {
                        long long v = ovf[i];
                        if ((int)(v >> 32) == row) {
                            int src = (int)(v & 0xffffffffLL);
                            if (f < CAP) acc += bf2f(xb[(size_t)src * 24 + f]);
                        }
                    }
                }
                acc *= 1.0f / (float)(c + 1);
            }
            s_a[node * 168 + t * 32 + f] = f2bf(acc);
        }
    }
    __syncthreads();

    // ---- phase L1: h1 = relu(s_a @ W1t + b1s), MFMA 16x16x32 ----
    int l = tid & 63, w = tid >> 6;
    int lr = l & 15, lg = l >> 4;
    {
        short8 a5[5];
        #pragma unroll
        for (int ks = 0; ks < 5; ++ks)
            a5[ks] = *(const short8*)&s_a[(w * 16 + lr) * 168 + ks * 32 + lg * 8];
        f32x4 acc[8];
        #pragma unroll
        for (int nt = 0; nt < 8; ++nt) acc[nt] = (f32x4){0.f, 0.f, 0.f, 0.f};
        #pragma unroll
        for (int nt = 0; nt < 8; ++nt) {
            #pragma unroll
            for (int ks = 0; ks < 5; ++ks) {
                short8 b = *(const short8*)&w1t[(nt * 16 + lr) * 160 + ks * 32 + lg * 8];
                acc[nt] = __builtin_amdgcn_mfma_f32_16x16x32_bf16(a5[ks], b, acc[nt], 0, 0, 0);
            }
        }
        #pragma unroll
        for (int nt = 0; nt < 8; ++nt) {
            float bias = b1s[nt * 16 + lr];
            #pragma unroll
            for (int r = 0; r < 4; ++r) {
                float h = acc[nt][r] + bias;
                s_h1[(w * 16 + lg * 4 + r) * 136 + nt * 16 + lr] = f2bf(h > 0.f ? h : 0.f);
            }
        }
    }
    __syncthreads();

    // ---- phase L2: per etype, g_t = h1 @ W2t ----
    short8 a2[4];
    #pragma unroll
    for (int ks = 0; ks < 4; ++ks)
        a2[ks] = *(const short8*)&s_h1[(w * 16 + lr) * 136 + ks * 32 + lg * 8];
    for (int t = gt0; t < gt1; ++t) {
        f32x4 acc2[4];
        #pragma unroll
        for (int nt = 0; nt < 4; ++nt) acc2[nt] = (f32x4){0.f, 0.f, 0.f, 0.f};
        #pragma unroll
        for (int nt = 0; nt < 4; ++nt) {
            #pragma unroll
            for (int ks = 0; ks < 4; ++ks) {
                short8 b = *(const short8*)&w2t[((size_t)t * OUT_DIM + nt * 16 + lr) * HID_DIM + ks * 32 + lg * 8];
                acc2[nt] = __builtin_amdgcn_mfma_f32_16x16x32_bf16(a2[ks], b, acc2[nt], 0, 0, 0);
            }
        }
        #pragma unroll
        for (int nt = 0; nt < 4; ++nt)
            #pragma unroll
            for (int r = 0; r < 4; ++r)
                s_out[(w * 16 + lg * 4 + r) * 72 + nt * 16 + lr] = f2bf(acc2[nt][r]);
        __syncthreads();
        size_t pb = (size_t)(t - gt0) * N_NODES;
        #pragma unroll
        for (int j = 0; j < 4; ++j) {
            int flat = j * 256 + tid;
            int rrow = flat >> 4, c4 = (flat & 15) * 4;
            int n = base + rrow;
            if (n < N_NODES)
                *(ushort4*)&g[(pb + n) * OUT_DIM + c4] = *(const ushort4*)&s_out[rrow * 72 + c4];
        }
        __syncthreads();
    }
}

// ---------------- layer-2 gather: wave per node, etype range, h2 bf16 ----------------
__global__ __launch_bounds__(256) void k_gather2f(const int* __restrict__ cnt,
                                                  const int* __restrict__ bucket,
                                                  const int* __restrict__ ovfn_g,
                                                  const long long* __restrict__ ovf,
                                                  const u16* __restrict__ g,
                                                  u16* __restrict__ h2,
                                                  int t0, int tcnt, int add) {
    int n = blockIdx.x * 4 + (threadIdx.x >> 6);
    int lane = threadIdx.x & 63;
    float acc = 0.f;
    for (int tc = 0; tc < tcnt; ++tc) {
        int row = (t0 + tc) * N_NODES + n;
        int c = cnt[row];
        float inv = 1.0f / (float)(c + 1);
        int bval = 0;
        if (lane < CAP) bval = bucket[(size_t)row * CAP + lane];
        int kmax = c < CAP ? c : CAP;
        const u16* gp = g + (size_t)tc * N_NODES * OUT_DIM;
        float s = bf2f(gp[(size_t)n * OUT_DIM + lane]);   // self
        for (int k = 0; k < kmax; ++k) {
            int src = __shfl(bval, k);
            s += bf2f(gp[(size_t)src * OUT_DIM + lane]);
        }
        if (c > CAP) {
            int nov = *ovfn_g; if (nov > OVF_ENTRIES) nov = OVF_ENTRIES;
            for (int i = 0; i < nov; ++i) {
                long long v = ovf[i];
                if ((int)(v >> 32) == row)
                    s += bf2f(gp[(size_t)(v & 0xffffffffLL) * OUT_DIM + lane]);
            }
        }
        acc += s * inv;
    }
    size_t oi = (size_t)n * OUT_DIM + lane;
    h2[oi] = f2bf(add ? bf2f(h2[oi]) + acc : acc);
}

// ---------------- pooling ----------------
__global__ __launch_bounds__(256) void k_pool(const u16* __restrict__ h2,
                                              const int* __restrict__ gids,
                                              const float* __restrict__ b2,
                                              float* __restrict__ out) {
    __shared__ float red[4][OUT_DIM];
    int gid = blockIdx.x;
    int lo = 0, hi = N_NODES;
    while (lo < hi) { int mid = (lo + hi) >> 1; if (gids[mid] < gid) lo = mid + 1; else hi = mid; }
    int start = lo;
    hi = N_NODES;
    while (lo < hi) { int mid = (lo + hi) >> 1; if (gids[mid] < gid + 1) lo = mid + 1; else hi = mid; }
    int end = lo;
    int count = end - start;
    int r = threadIdx.x >> 6, j = threadIdx.x & 63;
    float acc = 0.f;
    for (int n = start + r; n < end; n += 4)
        acc += bf2f(h2[(size_t)n * OUT_DIM + j]);
    red[r][j] = acc;
    __syncthreads();
    if (r == 0) {
        float total = red[0][j] + red[1][j] + red[2][j] + red[3][j];
        float b = 0.f;
        #pragma unroll
        for (int t = 0; t < N_ETYPES; ++t) b += b2[t * OUT_DIM + j];
        float c = (float)count;
        out[gid * OUT_DIM + j] = (total + c * b) / fmaxf(c, 1.0f);
    }
}

extern "C" void kernel_launch(void* const* d_in, const int* in_sizes, int n_in,
                              void* d_out, int out_size, void* d_ws, size_t ws_size,
                              hipStream_t stream) {
    const float* x    = (const float*)d_in[0];
    const int*   edges= (const int*)d_in[1];
    const int*   gids = (const int*)d_in[2];
    const float* W1   = (const float*)d_in[3];
    const float* b1   = (const float*)d_in[4];
    const float* W2   = (const float*)d_in[5];
    const float* b2   = (const float*)d_in[6];
    float* out = (float*)d_out;

    // word-offset workspace layout
    int*       cnt    = (int*)d_ws;                         // 500,000
    int*       ovfn   = cnt + 500000;                       // 1 (pad to 500,016)
    long long* ovf    = (long long*)(cnt + 500016);         // 8,192 words
    int*       bucket = cnt + 508208;                       // 500k*24 = 12,000,000
    u16*       xb     = (u16*)(cnt + 12508208);             // 1,200,000 words
    u16*       w1t    = (u16*)(cnt + 13708208);             // 10,240 words
    u16*       w2t    = (u16*)(cnt + 13718448);             // 20,480 words
    float*     b1s    = (float*)(cnt + 13738928);           // 128 (pad to 13,739,072)
    u16*       g      = (u16*)(cnt + 13739072);             // up to 16,000,000 words
    // single-pass: h2 after 5 g planes; fallback: after 3 g planes
    size_t need_single = 32939072ULL * 4;                   // 131.76 MB
    bool   single = ws_size >= need_single;
    u16*   h2 = (u16*)(cnt + (single ? 29739072 : 23339072));

    hipMemsetAsync(cnt, 0, 500016 * sizeof(int), stream);   // cnt + ovfn

    k_prep<<<80, 256, 0, stream>>>(W1, W2, b1, w1t, w2t, b1s);
    k_xb<<<(N_NODES * 24 + 255) / 256, 256, 0, stream>>>(x, xb);
    k_fill<<<dim3((N_EDGES + 255) / 256, N_ETYPES), 256, 0, stream>>>(edges, cnt, bucket, ovfn, ovf);

    int nblk = (N_NODES + 63) / 64;
    if (single) {
        k_fused<<<nblk, 256, 0, stream>>>(cnt, bucket, ovfn, ovf, xb, w1t, w2t, b1s, g, 0, 5);
        k_gather2f<<<N_NODES / 4, 256, 0, stream>>>(cnt, bucket, ovfn, ovf, g, h2, 0, 5, 0);
    } else {
        k_fused<<<nblk, 256, 0, stream>>>(cnt, bucket, ovfn, ovf, xb, w1t, w2t, b1s, g, 0, 3);
        k_gather2f<<<N_NODES / 4, 256, 0, stream>>>(cnt, bucket, ovfn, ovf, g, h2, 0, 3, 0);
        k_fused<<<nblk, 256, 0, stream>>>(cnt, bucket, ovfn, ovf, xb, w1t, w2t, b1s, g, 3, 5);
        k_gather2f<<<N_NODES / 4, 256, 0, stream>>>(cnt, bucket, ovfn, ovf, g, h2, 3, 2, 1);
    }
    k_pool<<<NUM_GRAPHS, 256, 0, stream>>>(h2, gids, b2, out);
}